// Round 3
// baseline (472.467 us; speedup 1.0000x reference)
//
#include <hip/hip_runtime.h>
#include <cstdint>
#include <cstddef>

#define VV 4
#define NN 2048
#define DDIM 128
#define KK 10
#define CAP 256

// Wave-local LDS ordering: waits outstanding DS ops, forbids compiler
// reordering. All inter-phase LDS sharing in fused_kernel is wave-private
// ([w]-indexed), so this suffices -- and it does NOT drain vmcnt.
#define WAVE_LDS_SYNC() asm volatile("s_waitcnt lgkmcnt(0)" ::: "memory")

__device__ __forceinline__ bool kgt(float v1, int i1, float v0, int i0) {
  // strict "greater" in top-k order: larger value wins; ties -> smaller index wins
  return (v1 > v0) || (v1 == v0 && i1 < i0);
}

// ---------------------------------------------------------------------------
// Kernel 1: per-view projections Qn/Kn/Vn = A @ W^T, plus per-block partial
// column sums of Vn (partialMV[v][blk][e]) for the later meanV reduction.
// (unchanged from verified version)
// ---------------------------------------------------------------------------
__global__ __launch_bounds__(256) void proj_kernel(
    const float* __restrict__ A, const float* __restrict__ WQ,
    const float* __restrict__ WK, const float* __restrict__ WV,
    float* __restrict__ Qn, float* __restrict__ Kn, float* __restrict__ Vn,
    float* __restrict__ partialMV)
{
  __shared__ float As[16][DDIM];      // A tile
  __shared__ float Ws[3][16][129];    // W chunk [mat][d][e], +1 pad breaks conflicts
  __shared__ float s_mv[2][DDIM];

  const int t    = threadIdx.x;
  const int v    = blockIdx.x >> 7;          // /128
  const int blk  = blockIdx.x & 127;
  const int n0   = blk * 16;
  const int e    = t & 127;
  const int half = t >> 7;

  float accq[8], acck[8], accv[8];
#pragma unroll
  for (int r = 0; r < 8; ++r) { accq[r] = 0.f; acck[r] = 0.f; accv[r] = 0.f; }

  const float* Ab = A + ((size_t)v * NN + n0) * DDIM;
#pragma unroll
  for (int k = 0; k < 2; ++k) {              // stage A tile (2048 floats, float4)
    int id4 = k * 256 + t;                   // 0..511
    int r   = id4 >> 5;
    int d4  = id4 & 31;
    float4 a4 = *(const float4*)(Ab + (size_t)id4 * 4);
    *(float4*)&As[r][d4 * 4] = a4;
  }
  const float* wqb = WQ + (size_t)v * DDIM * DDIM;
  const float* wkb = WK + (size_t)v * DDIM * DDIM;
  const float* wvb = WV + (size_t)v * DDIM * DDIM;

  for (int d0 = 0; d0 < DDIM; d0 += 16) {
    __syncthreads();                          // Ws free (and As staged on iter 0)
#pragma unroll
    for (int k = 0; k < 2; ++k) {             // stage W chunk: 128 e x 16 d per mat
      int id4 = k * 256 + t;                  // 0..511
      int ee  = id4 >> 2;
      int c4  = id4 & 3;
      const float4 wq4 = *(const float4*)(wqb + (size_t)ee * DDIM + d0 + c4 * 4);
      const float4 wk4 = *(const float4*)(wkb + (size_t)ee * DDIM + d0 + c4 * 4);
      const float4 wv4 = *(const float4*)(wvb + (size_t)ee * DDIM + d0 + c4 * 4);
      int dd = c4 * 4;
      Ws[0][dd + 0][ee] = wq4.x; Ws[0][dd + 1][ee] = wq4.y;
      Ws[0][dd + 2][ee] = wq4.z; Ws[0][dd + 3][ee] = wq4.w;
      Ws[1][dd + 0][ee] = wk4.x; Ws[1][dd + 1][ee] = wk4.y;
      Ws[1][dd + 2][ee] = wk4.z; Ws[1][dd + 3][ee] = wk4.w;
      Ws[2][dd + 0][ee] = wv4.x; Ws[2][dd + 1][ee] = wv4.y;
      Ws[2][dd + 2][ee] = wv4.z; Ws[2][dd + 3][ee] = wv4.w;
    }
    __syncthreads();
#pragma unroll
    for (int dd = 0; dd < 16; dd += 4) {
      float4 a[8];
#pragma unroll
      for (int r = 0; r < 8; ++r) a[r] = *(const float4*)&As[half * 8 + r][d0 + dd];
#pragma unroll
      for (int c = 0; c < 4; ++c) {
        float wq = Ws[0][dd + c][e];
        float wk = Ws[1][dd + c][e];
        float wv = Ws[2][dd + c][e];
#pragma unroll
        for (int r = 0; r < 8; ++r) {
          float av = ((const float*)&a[r])[c];
          accq[r] = fmaf(av, wq, accq[r]);
          acck[r] = fmaf(av, wk, acck[r]);
          accv[r] = fmaf(av, wv, accv[r]);
        }
      }
    }
  }

  const size_t ob = ((size_t)v * NN + n0 + half * 8) * DDIM + e;
#pragma unroll
  for (int r = 0; r < 8; ++r) {
    Qn[ob + (size_t)r * DDIM] = accq[r];
    Kn[ob + (size_t)r * DDIM] = acck[r];
    Vn[ob + (size_t)r * DDIM] = accv[r];
  }
  float s = 0.f;
#pragma unroll
  for (int r = 0; r < 8; ++r) s += accv[r];
  s_mv[half][e] = s;
  __syncthreads();
  if (half == 0)
    partialMV[((size_t)v * 128 + blk) * DDIM + e] = s + s_mv[1][e];
}

// ---------------------------------------------------------------------------
// Kernel 1b: finalize meanV[v][e] = sum_blk partialMV[v][blk][e] / 2048.
// ---------------------------------------------------------------------------
__global__ __launch_bounds__(128) void meanv_kernel(
    const float* __restrict__ partialMV, float* __restrict__ meanV)
{
  const int v = blockIdx.x;
  const int e = threadIdx.x;
  const float* pb = partialMV + (size_t)v * 128 * DDIM + e;
  float s0 = 0.f, s1 = 0.f, s2 = 0.f, s3 = 0.f;
#pragma unroll 8
  for (int b = 0; b < 128; b += 4) {
    s0 += pb[(size_t)(b + 0) * DDIM];
    s1 += pb[(size_t)(b + 1) * DDIM];
    s2 += pb[(size_t)(b + 2) * DDIM];
    s3 += pb[(size_t)(b + 3) * DDIM];
  }
  meanV[v * DDIM + e] = (s0 + s1 + s2 + s3) * (1.0f / 2048.0f);
}

// ---------------------------------------------------------------------------
// Kernel 2 (fused): per (p,n): top-10 of 3 off-diagonal C rows + scores +
// softmax(10) + aggregate (+ uniform diagonal term = meanV[p]).
// One wave per task; 2048 blocks x 256 thr; barrier-free.
// Changes vs round-1 (396 us) version:
//   - NO LDS prefetch pipeline (round-2 regression reverted: occupancy wins)
//   - single-pass scan+push: candidates pushed during the load scan; count
//     read back from s_cnt. Kills the separate count pass AND ends the row's
//     register live range before the sort -> much lower VGPR -> more waves.
//   - tier-2 (~1% rows) and general fallback re-read the row from L2 instead
//     of retaining 32 VGPRs of row data.
//   - __launch_bounds__(256,6) caps VGPR at ~85 as an occupancy floor.
// ---------------------------------------------------------------------------
__global__ __launch_bounds__(256, 6) void fused_kernel(
    const float* __restrict__ C, const float* __restrict__ Qn,
    const float* __restrict__ Kn, const float* __restrict__ Vn,
    const float* __restrict__ meanV, float* __restrict__ out)
{
  __shared__ float    s_val[4][CAP];
  __shared__ int      s_idx[4][CAP];
  __shared__ unsigned s_cnt[4];
  __shared__ float    s_sc[4][32];
  __shared__ float    s_al[4][32];
  __shared__ int      s_sel[4][32];

  const int t    = threadIdx.x;
  const int w    = t >> 6;
  const int lane = t & 63;
  const int task = blockIdx.x * 4 + w;       // 0..8191
  const int p    = task >> 11;               // same for all 4 waves of a block
  const int n    = task & 2047;
  const float SCALE = 0.08838834764831845f;  // 1/sqrt(128)

  // early per-lane register loads (issued long before use)
  const float* qrow = Qn + ((size_t)p * NN + n) * DDIM;
  float2 q2 = *(const float2*)(qrow + 2 * lane);
  float2 mv2 = *(const float2*)(meanV + p * DDIM + 2 * lane);
  q2.x *= SCALE; q2.y *= SCALE;

  // ---- per-wave: top-10 for each of the 3 off-diagonal q's ----
  for (int o = 0; o < 3; ++o) {
    const int q = o + (o >= p ? 1 : 0);
    const float* row = C + (((size_t)(p * 4 + q) * NN + n) << 11);

    // single-pass scan+push at threshold T; returns wave-uniform count.
    // (top-10 of candidates == global top-10 whenever count >= KK, since any
    //  top-10 value > T is by definition in the candidate set)
    const float T1 = 0.99f, T2 = 0.95f;
    int cnt;
    {
      if (lane == 0) s_cnt[w] = 0u;
      WAVE_LDS_SYNC();
#pragma unroll
      for (int i = 0; i < 8; ++i) {
        float4 vv = *(const float4*)(row + i * 256 + lane * 4);
        const float* pv = (const float*)&vv;
#pragma unroll
        for (int c = 0; c < 4; ++c) {
          if (pv[c] > T1) {
            unsigned pos = atomicAdd(&s_cnt[w], 1u);
            if (pos < CAP) {
              s_val[w][pos] = pv[c];
              s_idx[w][pos] = i * 256 + lane * 4 + c;
            }
          }
        }
      }
      WAVE_LDS_SYNC();
      cnt = (int)s_cnt[w];
    }
    bool ok = (cnt >= KK && cnt <= CAP);
    if (!ok) {                                // rare tier 2 (~1% of rows): rescan L2-hot row
      if (lane == 0) s_cnt[w] = 0u;
      WAVE_LDS_SYNC();
#pragma unroll
      for (int i = 0; i < 8; ++i) {
        float4 vv = *(const float4*)(row + i * 256 + lane * 4);
        const float* pv = (const float*)&vv;
#pragma unroll
        for (int c = 0; c < 4; ++c) {
          if (pv[c] > T2) {
            unsigned pos = atomicAdd(&s_cnt[w], 1u);
            if (pos < CAP) {
              s_val[w][pos] = pv[c];
              s_idx[w][pos] = i * 256 + lane * 4 + c;
            }
          }
        }
      }
      WAVE_LDS_SYNC();
      cnt = (int)s_cnt[w];
      ok  = (cnt >= KK && cnt <= CAP);
    }

    if (ok) {
      if (cnt <= 64) {
        // 64-lane bitonic sort, descending by (value, then smaller index)
        float kv = (lane < cnt) ? s_val[w][lane] : -1e30f;
        int   ki = (lane < cnt) ? s_idx[w][lane] : 0x7FFFFFFF;
#pragma unroll
        for (int k = 2; k <= 64; k <<= 1) {
#pragma unroll
          for (int j = k >> 1; j > 0; j >>= 1) {
            float ov = __shfl_xor(kv, j);
            int   oi = __shfl_xor(ki, j);
            bool dirDesc = (lane & k) == 0;
            bool lower   = (lane & j) == 0;
            bool ogt     = (ov > kv) || (ov == kv && oi < ki);
            bool take    = (dirDesc == lower) ? ogt : !ogt;
            if (take) { kv = ov; ki = oi; }
          }
        }
        if (lane < KK) s_sel[w][o * KK + lane] = ki;
      } else {
        // 65..256 candidates: 10 rounds of wave-argmax over 4 slots/lane
        float rv[4]; int ri[4];
#pragma unroll
        for (int s = 0; s < 4; ++s) {
          int  sl = lane + s * 64;
          bool in = sl < cnt;
          rv[s] = in ? s_val[w][sl] : -1e30f;
          ri[s] = in ? s_idx[w][sl] : 0x7FFFFFFF;
        }
        for (int r = 0; r < KK; ++r) {
          float lv = rv[0]; int li = ri[0]; int ls = 0;
#pragma unroll
          for (int s = 1; s < 4; ++s)
            if (kgt(rv[s], ri[s], lv, li)) { lv = rv[s]; li = ri[s]; ls = s; }
          float mv = lv; int mi = li;
#pragma unroll
          for (int off = 1; off < 64; off <<= 1) {
            float ov = __shfl_xor(mv, off);
            int   oi = __shfl_xor(mi, off);
            if (kgt(ov, oi, mv, mi)) { mv = ov; mi = oi; }
          }
          if (lane == 0) s_sel[w][o * KK + r] = mi;
          if (li == mi) {
#pragma unroll
            for (int s = 0; s < 4; ++s)
              if (ls == s) { rv[s] = -1e30f; ri[s] = 0x7FFFFFFF; }
          }
        }
      }
    } else {
      // fully general fallback (distribution-independent, ~never taken):
      // re-read the row (L2-hot) each argmax round; no retained row registers.
      unsigned consumed = 0;
      for (int r = 0; r < KK; ++r) {
        float lv = -1e30f; int li = 0x7FFFFFFF; int ls = 0;
#pragma unroll
        for (int i = 0; i < 8; ++i) {
          float4 vv = *(const float4*)(row + i * 256 + lane * 4);
          const float* pv = (const float*)&vv;
#pragma unroll
          for (int c = 0; c < 4; ++c) {
            int   sl = i * 4 + c;
            float x  = ((consumed >> sl) & 1u) ? -1e30f : pv[c];
            int   ix = i * 256 + lane * 4 + c;
            if (kgt(x, ix, lv, li)) { lv = x; li = ix; ls = sl; }
          }
        }
        float mv = lv; int mi = li;
#pragma unroll
        for (int off = 1; off < 64; off <<= 1) {
          float ov = __shfl_xor(mv, off);
          int   oi = __shfl_xor(mi, off);
          if (kgt(ov, oi, mv, mi)) { mv = ov; mi = oi; }
        }
        if (lane == 0) s_sel[w][o * KK + r] = mi;
        if (li == mi) consumed |= (1u << ls);
      }
    }
    WAVE_LDS_SYNC();
  }

  // ---- scores (Q . K_idx) for the 30 selected keys, d = (2*lane, 2*lane+1) ----
#pragma unroll
  for (int o = 0; o < 3; ++o) {
    const int q = o + (o >= p ? 1 : 0);
    const float* Kb = Kn + (size_t)q * NN * DDIM;
    int    sel[KK];
    float2 kv2[KK];
#pragma unroll
    for (int j = 0; j < KK; ++j) {            // issue all 10 gathers up front
      sel[j] = s_sel[w][o * KK + j];
      kv2[j] = *(const float2*)(Kb + (size_t)sel[j] * DDIM + 2 * lane);
    }
#pragma unroll
    for (int j = 0; j < KK; ++j) {
      float s = fmaf(q2.x, kv2[j].x, q2.y * kv2[j].y);
#pragma unroll
      for (int off = 32; off; off >>= 1) s += __shfl_xor(s, off);
      if (lane == 0) s_sc[w][o * KK + j] = s;
    }
  }
  WAVE_LDS_SYNC();

  // ---- per-q softmax over the 10 selected scores ----
  if (lane < 30) {
    const int b = (lane / KK) * KK;
    float m = s_sc[w][b];
#pragma unroll
    for (int j = 1; j < KK; ++j) m = fmaxf(m, s_sc[w][b + j]);
    float den = 0.f;
#pragma unroll
    for (int j = 0; j < KK; ++j) den += __expf(s_sc[w][b + j] - m);
    s_al[w][lane] = __expf(s_sc[w][lane] - m) / den;
  }
  WAVE_LDS_SYNC();

  // ---- aggregate: meanV[p] (diagonal) + sum_j alpha_j * Vn[q, idx_j] ----
  float2 acc = mv2;
#pragma unroll
  for (int o = 0; o < 3; ++o) {
    const int q = o + (o >= p ? 1 : 0);
    const float* Vb = Vn + (size_t)q * NN * DDIM;
    float2 vv2[KK]; float al[KK];
#pragma unroll
    for (int j = 0; j < KK; ++j) {            // issue all 10 gathers up front
      int s  = s_sel[w][o * KK + j];
      al[j]  = s_al[w][o * KK + j];
      vv2[j] = *(const float2*)(Vb + (size_t)s * DDIM + 2 * lane);
    }
#pragma unroll
    for (int j = 0; j < KK; ++j) {
      acc.x = fmaf(al[j], vv2[j].x, acc.x);
      acc.y = fmaf(al[j], vv2[j].y, acc.y);
    }
  }
  float* orow = out + ((size_t)p * NN + n) * DDIM;
  *(float2*)(orow + 2 * lane) = acc;
}

// ---------------------------------------------------------------------------
extern "C" void kernel_launch(void* const* d_in, const int* in_sizes, int n_in,
                              void* d_out, int out_size, void* d_ws, size_t ws_size,
                              hipStream_t stream)
{
  const float* A  = (const float*)d_in[0];
  const float* C  = (const float*)d_in[1];
  const float* WQ = (const float*)d_in[2];
  const float* WK = (const float*)d_in[3];
  const float* WV = (const float*)d_in[4];
  float* out = (float*)d_out;

  char* ws = (char*)d_ws;
  float* Qn        = (float*)ws;                               // 4 MB
  float* Kn        = (float*)(ws + (size_t)4 * 1024 * 1024);   // 4 MB
  float* Vn        = (float*)(ws + (size_t)8 * 1024 * 1024);   // 4 MB
  float* partialMV = (float*)(ws + (size_t)12 * 1024 * 1024);  // 256 KB
  float* meanV     = (float*)(ws + (size_t)12 * 1024 * 1024 + 256 * 1024); // 2 KB

  hipLaunchKernelGGL(proj_kernel, dim3(512), dim3(256), 0, stream,
                     A, WQ, WK, WV, Qn, Kn, Vn, partialMV);
  hipLaunchKernelGGL(meanv_kernel, dim3(4), dim3(128), 0, stream,
                     partialMV, meanV);
  hipLaunchKernelGGL(fused_kernel, dim3(2048), dim3(256), 0, stream,
                     C, Qn, Kn, Vn, meanV, out);
}

// Round 4
// 394.582 us; speedup vs baseline: 1.1974x; 1.1974x over previous
//
#include <hip/hip_runtime.h>
#include <cstdint>
#include <cstddef>

#define VV 4
#define NN 2048
#define DDIM 128
#define KK 10
#define CAP 256

// Wave-local LDS ordering: waits outstanding DS ops, forbids compiler
// reordering. All inter-phase LDS sharing in fused_kernel is wave-private
// ([w]-indexed), so this suffices -- and it does NOT drain vmcnt, so global
// loads stay in flight across phases.
#define WAVE_LDS_SYNC() asm volatile("s_waitcnt lgkmcnt(0)" ::: "memory")

__device__ __forceinline__ bool kgt(float v1, int i1, float v0, int i0) {
  // strict "greater" in top-k order: larger value wins; ties -> smaller index wins
  return (v1 > v0) || (v1 == v0 && i1 < i0);
}

// ---------------------------------------------------------------------------
// Kernel 1: per-view projections Qn/Kn/Vn = A @ W^T, plus per-block partial
// column sums of Vn (partialMV[v][blk][e]) for the later meanV reduction.
// (unchanged from verified version)
// ---------------------------------------------------------------------------
__global__ __launch_bounds__(256) void proj_kernel(
    const float* __restrict__ A, const float* __restrict__ WQ,
    const float* __restrict__ WK, const float* __restrict__ WV,
    float* __restrict__ Qn, float* __restrict__ Kn, float* __restrict__ Vn,
    float* __restrict__ partialMV)
{
  __shared__ float As[16][DDIM];      // A tile
  __shared__ float Ws[3][16][129];    // W chunk [mat][d][e], +1 pad breaks conflicts
  __shared__ float s_mv[2][DDIM];

  const int t    = threadIdx.x;
  const int v    = blockIdx.x >> 7;          // /128
  const int blk  = blockIdx.x & 127;
  const int n0   = blk * 16;
  const int e    = t & 127;
  const int half = t >> 7;

  float accq[8], acck[8], accv[8];
#pragma unroll
  for (int r = 0; r < 8; ++r) { accq[r] = 0.f; acck[r] = 0.f; accv[r] = 0.f; }

  const float* Ab = A + ((size_t)v * NN + n0) * DDIM;
#pragma unroll
  for (int k = 0; k < 2; ++k) {              // stage A tile (2048 floats, float4)
    int id4 = k * 256 + t;                   // 0..511
    int r   = id4 >> 5;
    int d4  = id4 & 31;
    float4 a4 = *(const float4*)(Ab + (size_t)id4 * 4);
    *(float4*)&As[r][d4 * 4] = a4;
  }
  const float* wqb = WQ + (size_t)v * DDIM * DDIM;
  const float* wkb = WK + (size_t)v * DDIM * DDIM;
  const float* wvb = WV + (size_t)v * DDIM * DDIM;

  for (int d0 = 0; d0 < DDIM; d0 += 16) {
    __syncthreads();                          // Ws free (and As staged on iter 0)
#pragma unroll
    for (int k = 0; k < 2; ++k) {             // stage W chunk: 128 e x 16 d per mat
      int id4 = k * 256 + t;                  // 0..511
      int ee  = id4 >> 2;
      int c4  = id4 & 3;
      const float4 wq4 = *(const float4*)(wqb + (size_t)ee * DDIM + d0 + c4 * 4);
      const float4 wk4 = *(const float4*)(wkb + (size_t)ee * DDIM + d0 + c4 * 4);
      const float4 wv4 = *(const float4*)(wvb + (size_t)ee * DDIM + d0 + c4 * 4);
      int dd = c4 * 4;
      Ws[0][dd + 0][ee] = wq4.x; Ws[0][dd + 1][ee] = wq4.y;
      Ws[0][dd + 2][ee] = wq4.z; Ws[0][dd + 3][ee] = wq4.w;
      Ws[1][dd + 0][ee] = wk4.x; Ws[1][dd + 1][ee] = wk4.y;
      Ws[1][dd + 2][ee] = wk4.z; Ws[1][dd + 3][ee] = wk4.w;
      Ws[2][dd + 0][ee] = wv4.x; Ws[2][dd + 1][ee] = wv4.y;
      Ws[2][dd + 2][ee] = wv4.z; Ws[2][dd + 3][ee] = wv4.w;
    }
    __syncthreads();
#pragma unroll
    for (int dd = 0; dd < 16; dd += 4) {
      float4 a[8];
#pragma unroll
      for (int r = 0; r < 8; ++r) a[r] = *(const float4*)&As[half * 8 + r][d0 + dd];
#pragma unroll
      for (int c = 0; c < 4; ++c) {
        float wq = Ws[0][dd + c][e];
        float wk = Ws[1][dd + c][e];
        float wv = Ws[2][dd + c][e];
#pragma unroll
        for (int r = 0; r < 8; ++r) {
          float av = ((const float*)&a[r])[c];
          accq[r] = fmaf(av, wq, accq[r]);
          acck[r] = fmaf(av, wk, acck[r]);
          accv[r] = fmaf(av, wv, accv[r]);
        }
      }
    }
  }

  const size_t ob = ((size_t)v * NN + n0 + half * 8) * DDIM + e;
#pragma unroll
  for (int r = 0; r < 8; ++r) {
    Qn[ob + (size_t)r * DDIM] = accq[r];
    Kn[ob + (size_t)r * DDIM] = acck[r];
    Vn[ob + (size_t)r * DDIM] = accv[r];
  }
  float s = 0.f;
#pragma unroll
  for (int r = 0; r < 8; ++r) s += accv[r];
  s_mv[half][e] = s;
  __syncthreads();
  if (half == 0)
    partialMV[((size_t)v * 128 + blk) * DDIM + e] = s + s_mv[1][e];
}

// ---------------------------------------------------------------------------
// Kernel 1b: finalize meanV[v][e] = sum_blk partialMV[v][blk][e] / 2048.
// ---------------------------------------------------------------------------
__global__ __launch_bounds__(128) void meanv_kernel(
    const float* __restrict__ partialMV, float* __restrict__ meanV)
{
  const int v = blockIdx.x;
  const int e = threadIdx.x;
  const float* pb = partialMV + (size_t)v * 128 * DDIM + e;
  float s0 = 0.f, s1 = 0.f, s2 = 0.f, s3 = 0.f;
#pragma unroll 8
  for (int b = 0; b < 128; b += 4) {
    s0 += pb[(size_t)(b + 0) * DDIM];
    s1 += pb[(size_t)(b + 1) * DDIM];
    s2 += pb[(size_t)(b + 2) * DDIM];
    s3 += pb[(size_t)(b + 3) * DDIM];
  }
  meanV[v * DDIM + e] = (s0 + s1 + s2 + s3) * (1.0f / 2048.0f);
}

// ---------------------------------------------------------------------------
// Kernel 2 (fused): per (p,n): top-10 of 3 off-diagonal C rows + scores +
// softmax(10) + aggregate (+ uniform diagonal term = meanV[p]).
// One wave per task; 2048 blocks x 256 thr; barrier-free.
// Round-4 changes:
//   - topk phase restored to the verified round-1 structure: row fully in
//     registers, count from registers (pure VALU), push once at final T.
//     (Round 3's in-scan pushes serialized the 8 row loads behind exec-masked
//      LDS atomics -> 8 exposed HBM latencies per row, +76 us. Reverted.)
//   - register double-buffer across rows: row0->a, row1->b issued back to
//     back at kernel top; topk(0,a) hides row1's flight; row2 reloads a and
//     flies during topk(1,b). One exposed row latency per wave instead of 3.
//     Registers, not LDS (round 2's LDS variant cost blocks/CU; VGPRs are
//     free here -- round-3 measured occupancy 45% is not resource-capped).
// ---------------------------------------------------------------------------
__global__ __launch_bounds__(256) void fused_kernel(
    const float* __restrict__ C, const float* __restrict__ Qn,
    const float* __restrict__ Kn, const float* __restrict__ Vn,
    const float* __restrict__ meanV, float* __restrict__ out)
{
  __shared__ float    s_val[4][CAP];
  __shared__ int      s_idx[4][CAP];
  __shared__ unsigned s_cnt[4];
  __shared__ float    s_sc[4][32];
  __shared__ float    s_al[4][32];
  __shared__ int      s_sel[4][32];

  const int t    = threadIdx.x;
  const int w    = t >> 6;
  const int lane = t & 63;
  const int task = blockIdx.x * 4 + w;       // 0..8191
  const int p    = task >> 11;               // same for all 4 waves of a block
  const int n    = task & 2047;
  const float SCALE = 0.08838834764831845f;  // 1/sqrt(128)

  // off-diagonal q's and C-row base pointers
  const int q_0 = (0 >= p) ? 1 : 0;
  const int q_1 = (1 >= p) ? 2 : 1;
  const int q_2 = (2 >= p) ? 3 : 2;
  const float* row0p = C + (((size_t)(p * 4 + q_0) * NN + n) << 11);
  const float* row1p = C + (((size_t)(p * 4 + q_1) * NN + n) << 11);
  const float* row2p = C + (((size_t)(p * 4 + q_2) * NN + n) << 11);

  // register double-buffer: issue row0 and row1 loads back-to-back.
  float4 a[8], b[8];
#pragma unroll
  for (int i = 0; i < 8; ++i) a[i] = *(const float4*)(row0p + i * 256 + lane * 4);
#pragma unroll
  for (int i = 0; i < 8; ++i) b[i] = *(const float4*)(row1p + i * 256 + lane * 4);

  // early per-lane register loads (used much later)
  const float* qrow = Qn + ((size_t)p * NN + n) * DDIM;
  float2 q2 = *(const float2*)(qrow + 2 * lane);
  float2 mv2 = *(const float2*)(meanV + p * DDIM + 2 * lane);
  q2.x *= SCALE; q2.y *= SCALE;

  // ---- verified round-1 topk body, on a register-resident row ----
  auto do_topk = [&](int o, const float4 (&vv)[8]) {
    if (lane == 0) s_cnt[w] = 0u;

    const float T1 = 0.99f, T2 = 0.95f;
    int c1 = 0;
#pragma unroll
    for (int i = 0; i < 8; ++i) {
      const float* pv = (const float*)&vv[i];
#pragma unroll
      for (int c = 0; c < 4; ++c) c1 += (pv[c] > T1) ? 1 : 0;
    }
#pragma unroll
    for (int off = 32; off; off >>= 1) c1 += __shfl_xor(c1, off);

    float T = T1; int cnt = c1; bool ok = (c1 >= KK && c1 <= CAP);
    if (!ok) {                                // rare tier 2
      int c2 = 0;
#pragma unroll
      for (int i = 0; i < 8; ++i) {
        const float* pv = (const float*)&vv[i];
#pragma unroll
        for (int c = 0; c < 4; ++c) c2 += (pv[c] > T2) ? 1 : 0;
      }
#pragma unroll
      for (int off = 32; off; off >>= 1) c2 += __shfl_xor(c2, off);
      T = T2; cnt = c2; ok = (c2 >= KK && c2 <= CAP);
    }

    if (ok) {
#pragma unroll
      for (int i = 0; i < 8; ++i) {
        const float* pv = (const float*)&vv[i];
#pragma unroll
        for (int c = 0; c < 4; ++c) {
          float x = pv[c];
          if (x > T) {
            unsigned pos = atomicAdd(&s_cnt[w], 1u);
            s_val[w][pos] = x;
            s_idx[w][pos] = i * 256 + lane * 4 + c;
          }
        }
      }
      WAVE_LDS_SYNC();
      if (cnt <= 64) {
        // 64-lane bitonic sort, descending by (value, then smaller index)
        float kv = (lane < cnt) ? s_val[w][lane] : -1e30f;
        int   ki = (lane < cnt) ? s_idx[w][lane] : 0x7FFFFFFF;
#pragma unroll
        for (int k = 2; k <= 64; k <<= 1) {
#pragma unroll
          for (int j = k >> 1; j > 0; j >>= 1) {
            float ov = __shfl_xor(kv, j);
            int   oi = __shfl_xor(ki, j);
            bool dirDesc = (lane & k) == 0;
            bool lower   = (lane & j) == 0;
            bool ogt     = (ov > kv) || (ov == kv && oi < ki);
            bool take    = (dirDesc == lower) ? ogt : !ogt;
            if (take) { kv = ov; ki = oi; }
          }
        }
        if (lane < KK) s_sel[w][o * KK + lane] = ki;
      } else {
        // 65..256 candidates: 10 rounds of wave-argmax over 4 slots/lane
        float rv[4]; int ri[4];
#pragma unroll
        for (int s = 0; s < 4; ++s) {
          int  sl = lane + s * 64;
          bool in = sl < cnt;
          rv[s] = in ? s_val[w][sl] : -1e30f;
          ri[s] = in ? s_idx[w][sl] : 0x7FFFFFFF;
        }
        for (int r = 0; r < KK; ++r) {
          float lv = rv[0]; int li = ri[0]; int ls = 0;
#pragma unroll
          for (int s = 1; s < 4; ++s)
            if (kgt(rv[s], ri[s], lv, li)) { lv = rv[s]; li = ri[s]; ls = s; }
          float mv = lv; int mi = li;
#pragma unroll
          for (int off = 1; off < 64; off <<= 1) {
            float ov = __shfl_xor(mv, off);
            int   oi = __shfl_xor(mi, off);
            if (kgt(ov, oi, mv, mi)) { mv = ov; mi = oi; }
          }
          if (lane == 0) s_sel[w][o * KK + r] = mi;
          if (li == mi) {
#pragma unroll
            for (int s = 0; s < 4; ++s)
              if (ls == s) { rv[s] = -1e30f; ri[s] = 0x7FFFFFFF; }
          }
        }
      }
    } else {
      // fully general fallback (distribution-independent, ~never taken)
      unsigned consumed = 0;
      for (int r = 0; r < KK; ++r) {
        float lv = -1e30f; int li = 0x7FFFFFFF; int ls = 0;
#pragma unroll
        for (int i = 0; i < 8; ++i) {
          const float* pv = (const float*)&vv[i];
#pragma unroll
          for (int c = 0; c < 4; ++c) {
            int   sl = i * 4 + c;
            float x  = ((consumed >> sl) & 1u) ? -1e30f : pv[c];
            int   ix = i * 256 + lane * 4 + c;
            if (kgt(x, ix, lv, li)) { lv = x; li = ix; ls = sl; }
          }
        }
        float mv = lv; int mi = li;
#pragma unroll
        for (int off = 1; off < 64; off <<= 1) {
          float ov = __shfl_xor(mv, off);
          int   oi = __shfl_xor(mi, off);
          if (kgt(ov, oi, mv, mi)) { mv = ov; mi = oi; }
        }
        if (lane == 0) s_sel[w][o * KK + r] = mi;
        if (li == mi) consumed |= (1u << ls);
      }
    }
    WAVE_LDS_SYNC();
  };

  // pipeline: topk(0,a) hides row1's flight; row2 reloads a during topk(1,b)
  do_topk(0, a);
#pragma unroll
  for (int i = 0; i < 8; ++i) a[i] = *(const float4*)(row2p + i * 256 + lane * 4);
  do_topk(1, b);
  do_topk(2, a);

  // ---- scores (Q . K_idx) for the 30 selected keys, d = (2*lane, 2*lane+1) ----
#pragma unroll
  for (int o = 0; o < 3; ++o) {
    const int q = o + (o >= p ? 1 : 0);
    const float* Kb = Kn + (size_t)q * NN * DDIM;
    int    sel[KK];
    float2 kv2[KK];
#pragma unroll
    for (int j = 0; j < KK; ++j) {            // issue all 10 gathers up front
      sel[j] = s_sel[w][o * KK + j];
      kv2[j] = *(const float2*)(Kb + (size_t)sel[j] * DDIM + 2 * lane);
    }
#pragma unroll
    for (int j = 0; j < KK; ++j) {
      float s = fmaf(q2.x, kv2[j].x, q2.y * kv2[j].y);
#pragma unroll
      for (int off = 32; off; off >>= 1) s += __shfl_xor(s, off);
      if (lane == 0) s_sc[w][o * KK + j] = s;
    }
  }
  WAVE_LDS_SYNC();

  // ---- per-q softmax over the 10 selected scores ----
  if (lane < 30) {
    const int b2 = (lane / KK) * KK;
    float m = s_sc[w][b2];
#pragma unroll
    for (int j = 1; j < KK; ++j) m = fmaxf(m, s_sc[w][b2 + j]);
    float den = 0.f;
#pragma unroll
    for (int j = 0; j < KK; ++j) den += __expf(s_sc[w][b2 + j] - m);
    s_al[w][lane] = __expf(s_sc[w][lane] - m) / den;
  }
  WAVE_LDS_SYNC();

  // ---- aggregate: meanV[p] (diagonal) + sum_j alpha_j * Vn[q, idx_j] ----
  float2 acc = mv2;
#pragma unroll
  for (int o = 0; o < 3; ++o) {
    const int q = o + (o >= p ? 1 : 0);
    const float* Vb = Vn + (size_t)q * NN * DDIM;
    float2 vv2[KK]; float al[KK];
#pragma unroll
    for (int j = 0; j < KK; ++j) {            // issue all 10 gathers up front
      int s  = s_sel[w][o * KK + j];
      al[j]  = s_al[w][o * KK + j];
      vv2[j] = *(const float2*)(Vb + (size_t)s * DDIM + 2 * lane);
    }
#pragma unroll
    for (int j = 0; j < KK; ++j) {
      acc.x = fmaf(al[j], vv2[j].x, acc.x);
      acc.y = fmaf(al[j], vv2[j].y, acc.y);
    }
  }
  float* orow = out + ((size_t)p * NN + n) * DDIM;
  *(float2*)(orow + 2 * lane) = acc;
}

// ---------------------------------------------------------------------------
extern "C" void kernel_launch(void* const* d_in, const int* in_sizes, int n_in,
                              void* d_out, int out_size, void* d_ws, size_t ws_size,
                              hipStream_t stream)
{
  const float* A  = (const float*)d_in[0];
  const float* C  = (const float*)d_in[1];
  const float* WQ = (const float*)d_in[2];
  const float* WK = (const float*)d_in[3];
  const float* WV = (const float*)d_in[4];
  float* out = (float*)d_out;

  char* ws = (char*)d_ws;
  float* Qn        = (float*)ws;                               // 4 MB
  float* Kn        = (float*)(ws + (size_t)4 * 1024 * 1024);   // 4 MB
  float* Vn        = (float*)(ws + (size_t)8 * 1024 * 1024);   // 4 MB
  float* partialMV = (float*)(ws + (size_t)12 * 1024 * 1024);  // 256 KB
  float* meanV     = (float*)(ws + (size_t)12 * 1024 * 1024 + 256 * 1024); // 2 KB

  hipLaunchKernelGGL(proj_kernel, dim3(512), dim3(256), 0, stream,
                     A, WQ, WK, WV, Qn, Kn, Vn, partialMV);
  hipLaunchKernelGGL(meanv_kernel, dim3(4), dim3(128), 0, stream,
                     partialMV, meanV);
  hipLaunchKernelGGL(fused_kernel, dim3(2048), dim3(256), 0, stream,
                     C, Qn, Kn, Vn, meanV, out);
}